// Round 13
// baseline (426.204 us; speedup 1.0000x reference)
//
#include <hip/hip_runtime.h>

#define N_NODES 50000
#define N_EDGES 600000
#define DD 128

typedef __attribute__((ext_vector_type(8))) short short8;
typedef __attribute__((ext_vector_type(4))) float f32x4;

__device__ __forceinline__ short f2bf(float f) {
    union { float f; unsigned u; } v; v.f = f;
    unsigned r = v.u + 0x7fffu + ((v.u >> 16) & 1u);
    return (short)(r >> 16);
}
__device__ __forceinline__ float u2f(unsigned u) {
    union { float f; unsigned u; } v; v.u = u;
    return v.f;
}
__device__ __forceinline__ unsigned packbf(float a, float b) {
    return ((unsigned)(unsigned short)f2bf(a)) |
           (((unsigned)(unsigned short)f2bf(b)) << 16);
}

// ---------------------------------------------------------------------------
// Streaming GEMM: Y = X @ W^T + bias -> bf16 (obj_lin). W frag-major in LDS.
// (proven)
// ---------------------------------------------------------------------------
__global__ __launch_bounds__(256) void k_lin(const float* __restrict__ X,
                                             const float* __restrict__ W,
                                             const float* __restrict__ bias,
                                             short* __restrict__ Y,
                                             int ntiles) {
    __shared__ __align__(16) short Wf[128 * 128];
    for (int i = threadIdx.x; i < 2048; i += 256) {
        const int fl = i & 63, fr = i >> 6;
        const int nt = fr >> 2, ks = fr & 3, fg = fl >> 4, fln = fl & 15;
        const float* s = W + (nt * 16 + fln) * DD + ks * 32 + fg * 8;
        short* d = Wf + i * 8;
#pragma unroll
        for (int j = 0; j < 8; ++j) d[j] = f2bf(s[j]);
    }
    __syncthreads();

    const int wave = threadIdx.x >> 6;
    const int lane = threadIdx.x & 63;
    const int g = lane >> 4, ln = lane & 15;

    float bb[8];
#pragma unroll
    for (int nt = 0; nt < 8; ++nt) bb[nt] = bias[nt * 16 + ln];

    for (int t = blockIdx.x * 4 + wave; t < ntiles; t += gridDim.x * 4) {
        const float* xr = X + (size_t)(t * 16 + ln) * DD;
        short8 a[4];
#pragma unroll
        for (int ks = 0; ks < 4; ++ks) {
            const f32x4* p = (const f32x4*)(xr + ks * 32 + g * 8);
            const f32x4 t0 = __builtin_nontemporal_load(p);
            const f32x4 t1 = __builtin_nontemporal_load(p + 1);
            short8 v;
            v[0] = f2bf(t0[0]); v[1] = f2bf(t0[1]); v[2] = f2bf(t0[2]); v[3] = f2bf(t0[3]);
            v[4] = f2bf(t1[0]); v[5] = f2bf(t1[1]); v[6] = f2bf(t1[2]); v[7] = f2bf(t1[3]);
            a[ks] = v;
        }
#pragma unroll
        for (int nt = 0; nt < 8; ++nt) {
            f32x4 acc = {0.f, 0.f, 0.f, 0.f};
#pragma unroll
            for (int ks = 0; ks < 4; ++ks) {
                short8 b = *(const short8*)(Wf + (((nt << 2) + ks) * 64 + lane) * 8);
                acc = __builtin_amdgcn_mfma_f32_16x16x32_bf16(a[ks], b, acc, 0, 0, 0);
            }
#pragma unroll
            for (int r = 0; r < 4; ++r)
                Y[(size_t)(t * 16 + g * 4 + r) * DD + nt * 16 + ln] = f2bf(acc[r] + bb[nt]);
        }
    }
}

// ---------------------------------------------------------------------------
// CSR-rank construction (counts zeroed by hipMemsetAsync)
// ---------------------------------------------------------------------------
__global__ __launch_bounds__(256) void k_count(const int* __restrict__ EI,
                                               int* __restrict__ counts) {
    int e = blockIdx.x * 256 + threadIdx.x;
    if (e < N_EDGES) atomicAdd(&counts[EI[2 * e + 1]], 1);
}

__global__ __launch_bounds__(256) void k_scan1(const int* __restrict__ counts,
                                               int* __restrict__ scanned,
                                               int* __restrict__ bsum) {
    __shared__ int tmp[256];
    const int t = threadIdx.x;
    const int i = blockIdx.x * 256 + t;
    int v = (i < N_NODES) ? counts[i] : 0;
    tmp[t] = v;
    __syncthreads();
#pragma unroll
    for (int off = 1; off < 256; off <<= 1) {
        int x = (t >= off) ? tmp[t - off] : 0;
        __syncthreads();
        tmp[t] += x;
        __syncthreads();
    }
    if (i < N_NODES) scanned[i] = tmp[t] - v;
    if (t == 255) bsum[blockIdx.x] = tmp[255];
}

__global__ __launch_bounds__(256) void k_scan3m(const int* __restrict__ scanned,
                                                const int* __restrict__ bsum,
                                                int* __restrict__ offsets,
                                                int* __restrict__ cursor,
                                                int nb) {
    __shared__ int red[256];
    const int t = threadIdx.x;
    const int bid = blockIdx.x;
    red[t] = (t < bid && t < nb) ? bsum[t] : 0;
    __syncthreads();
#pragma unroll
    for (int off = 128; off > 0; off >>= 1) {
        if (t < off) red[t] += red[t + off];
        __syncthreads();
    }
    const int pre = red[0];
    const int i = bid * 256 + t;
    if (i < N_NODES) {
        const int off = scanned[i] + pre;
        offsets[i] = off;
        cursor[i] = off;
    }
    if (i == 0) offsets[N_NODES] = N_EDGES;
}

__global__ __launch_bounds__(256) void k_scatter2(const int* __restrict__ EI,
                                                  int* __restrict__ cursor,
                                                  int* __restrict__ perm) {
    int e = blockIdx.x * 256 + threadIdx.x;
    if (e < N_EDGES)
        perm[e] = atomicAdd(&cursor[EI[2 * e + 1]], 1);
}

// ---------------------------------------------------------------------------
// Fused rel-GEMM + OL[src] add + scatter-write to dst-sorted position.
// LDS trimmed to exactly 40960B (Wf 32KB + stg 8KB) -> 4 blocks/CU.
// Two-pass epilogue (8 edges/pass): stage -> batched OL gathers -> store.
// ---------------------------------------------------------------------------
__global__ __launch_bounds__(256, 4) void k_fl(const float* __restrict__ RV,
                                               const int* __restrict__ EI,
                                               const int* __restrict__ perm,
                                               const float* __restrict__ W,
                                               const float* __restrict__ bias,
                                               const short* __restrict__ OL,
                                               unsigned* __restrict__ Ysw) {
    __shared__ __align__(16) short Wf[128 * 128];
    __shared__ __align__(16) unsigned stg[4][512];   // per-wave 4 rows x 128 words

    for (int i = threadIdx.x; i < 2048; i += 256) {
        const int fl = i & 63, fr = i >> 6;
        const int nt = fr >> 2, ks = fr & 3, fg = fl >> 4, fln = fl & 15;
        const float* s = W + (nt * 16 + fln) * DD + ks * 32 + fg * 8;
        short* d = Wf + i * 8;
#pragma unroll
        for (int j = 0; j < 8; ++j) d[j] = f2bf(s[j]);
    }
    __syncthreads();

    const int wave = threadIdx.x >> 6;
    const int lane = threadIdx.x & 63;
    const int g = lane >> 4, ln = lane & 15;
    unsigned* st = stg[wave];

    const float br0 = bias[2 * lane];
    const float br1 = bias[2 * lane + 1];
    const unsigned short* OLu = (const unsigned short*)OL;
    const int NT = N_EDGES / 16;                      // 37500 exact

    for (int t = blockIdx.x * 4 + wave; t < NT; t += gridDim.x * 4) {
        const int e0 = t * 16;

        // A-fragment: row ln <- rel_vecs[e0+ln] (sequential stream, nt-load)
        const float* xr = RV + (size_t)(e0 + ln) * DD;
        short8 a[4];
#pragma unroll
        for (int ks = 0; ks < 4; ++ks) {
            const f32x4* p = (const f32x4*)(xr + ks * 32 + g * 8);
            const f32x4 t0 = __builtin_nontemporal_load(p);
            const f32x4 t1 = __builtin_nontemporal_load(p + 1);
            short8 v;
            v[0] = f2bf(t0[0]); v[1] = f2bf(t0[1]); v[2] = f2bf(t0[2]); v[3] = f2bf(t0[3]);
            v[4] = f2bf(t1[0]); v[5] = f2bf(t1[1]); v[6] = f2bf(t1[2]); v[7] = f2bf(t1[3]);
            a[ks] = v;
        }

        // src + sorted position for the 16 edges (lanes 0..15 hold, shfl later)
        int sp = 0, pp = 0;
        if (lane < 16) {
            sp = EI[2 * (e0 + lane)];
            pp = perm[e0 + lane];
        }

        f32x4 acc[8];
#pragma unroll
        for (int nt = 0; nt < 8; ++nt) {
            acc[nt] = (f32x4){0.f, 0.f, 0.f, 0.f};
#pragma unroll
            for (int ks = 0; ks < 4; ++ks) {
                short8 b = *(const short8*)(Wf + (((nt << 2) + ks) * 64 + lane) * 8);
                acc[nt] = __builtin_amdgcn_mfma_f32_16x16x32_bf16(a[ks], b, acc[nt], 0, 0, 0);
            }
        }

        // two passes of 8 edges: pass 0 -> g in {0,1}, pass 1 -> g in {2,3}
#pragma unroll
        for (int pass = 0; pass < 2; ++pass) {
            // stage: owning lanes write rows (g&1)*2, (g&1)*2+1 (stride 128)
            if ((g >> 1) == pass) {
#pragma unroll
                for (int nt = 0; nt < 8; ++nt) {
                    const int c = nt * 16 + ln;
                    st[((g & 1) * 2) * 128 + c]     = packbf(acc[nt][0], acc[nt][1]);
                    st[((g & 1) * 2 + 1) * 128 + c] = packbf(acc[nt][2], acc[nt][3]);
                }
            }
            // batched gathers: all 8 OL words + positions first (max MLP)
            unsigned ol8[8];
            int pos8[8];
#pragma unroll
            for (int e8 = 0; e8 < 8; ++e8) {
                const int e = pass * 8 + e8;
                const int src = __shfl(sp, e);
                pos8[e8] = __shfl(pp, e);
                ol8[e8] = *(const unsigned*)(OLu + (size_t)src * DD + 2 * lane);
            }
            // compute + scatter stores
#pragma unroll
            for (int ep = 0; ep < 4; ++ep) {
                const unsigned qx = st[ep * 128 + 2 * lane];
                const unsigned qy = st[ep * 128 + 2 * lane + 1];
#pragma unroll
                for (int sub = 0; sub < 2; ++sub) {
                    const int e8 = 2 * ep + sub;
                    const float s0 = sub ? u2f(qx & 0xffff0000u) : u2f(qx << 16);
                    const float s1 = sub ? u2f(qy & 0xffff0000u) : u2f(qy << 16);
                    const float y0 = s0 + br0 + u2f(ol8[e8] << 16);
                    const float y1 = s1 + br1 + u2f(ol8[e8] & 0xffff0000u);
                    Ysw[(size_t)pos8[e8] * (DD / 2) + lane] = packbf(y0, y1);
                }
            }
        }
    }
}

// ---------------------------------------------------------------------------
// Segment sum: one wave per node; lanes 0-31 even rows, 32-63 odd rows,
// 8B loads; shfl_xor(32) finish. Writes every node (deg-0 -> 0).
// ---------------------------------------------------------------------------
__global__ __launch_bounds__(256) void k_segsum(const unsigned* __restrict__ Ysw,
                                                const short* __restrict__ OL,
                                                const int* __restrict__ offs,
                                                float* __restrict__ out) {
    const int wave = threadIdx.x >> 6;
    const int lane = threadIdx.x & 63;
    const int v = blockIdx.x * 4 + wave;
    if (v >= N_NODES) return;

    const int r0 = offs[v], r1 = offs[v + 1];
    const int half = lane >> 5;
    const int q = lane & 31;
    const unsigned short* OLu = (const unsigned short*)OL;

    const uint2 odw = *(const uint2*)(OLu + (size_t)v * DD + 4 * q);
    const float od0 = u2f(odw.x << 16), od1 = u2f(odw.x & 0xffff0000u);
    const float od2 = u2f(odw.y << 16), od3 = u2f(odw.y & 0xffff0000u);

    float a0 = 0.f, a1 = 0.f, a2 = 0.f, a3 = 0.f;
    for (int r = r0 + half; r < r1; r += 2) {
        const uint2 y = *(const uint2*)(Ysw + (size_t)r * (DD / 2) + 2 * q);
        a0 += fmaxf(u2f(y.x << 16) + od0, 0.f);
        a1 += fmaxf(u2f(y.x & 0xffff0000u) + od1, 0.f);
        a2 += fmaxf(u2f(y.y << 16) + od2, 0.f);
        a3 += fmaxf(u2f(y.y & 0xffff0000u) + od3, 0.f);
    }
    a0 += __shfl_xor(a0, 32);
    a1 += __shfl_xor(a1, 32);
    a2 += __shfl_xor(a2, 32);
    a3 += __shfl_xor(a3, 32);

    if (half == 0) {
        float4 o;
        o.x = fmaxf(a0, 0.f); o.y = fmaxf(a1, 0.f);
        o.z = fmaxf(a2, 0.f); o.w = fmaxf(a3, 0.f);
        *(float4*)(out + (size_t)v * DD + 4 * q) = o;
    }
}

// ---------------------------------------------------------------------------
extern "C" void kernel_launch(void* const* d_in, const int* in_sizes, int n_in,
                              void* d_out, int out_size, void* d_ws, size_t ws_size,
                              hipStream_t stream) {
    const float* obj = (const float*)d_in[0];
    const float* rel = (const float*)d_in[1];
    const int*   ei  = (const int*)d_in[2];
    const float* Wo  = (const float*)d_in[3];
    const float* bo  = (const float*)d_in[4];
    const float* Wr  = (const float*)d_in[5];
    const float* br  = (const float*)d_in[6];
    float* out = (float*)d_out;

    char* ws = (char*)d_ws;
    unsigned* Ysw  = (unsigned*)ws;                  // 153,600,000 B
    short* OLb     = (short*)(ws + 153600000);       //  12,800,000 B
    int*   perm    = (int*)(ws + 166400000);         //   2,400,000 B
    int*   counts  = (int*)(ws + 168800000);         //     200,000 B
    int*   scanned = (int*)(ws + 169000192);         //     200,704 B
    int*   offsets = (int*)(ws + 169200896);         //     200,704 B (50001 ints)
    int*   cursor  = (int*)(ws + 169401600);         //     200,000 B
    int*   bsum    = (int*)(ws + 169601792);         //       1,024 B

    const int NB_E = (N_EDGES + 255) / 256;          // 2344
    const int NB_N = (N_NODES + 255) / 256;          // 196

    hipMemsetAsync(counts, 0, N_NODES * sizeof(int), stream);
    k_count<<<NB_E, 256, 0, stream>>>(ei, counts);
    k_scan1<<<NB_N, 256, 0, stream>>>(counts, scanned, bsum);
    k_scan3m<<<NB_N, 256, 0, stream>>>(scanned, bsum, offsets, cursor, NB_N);
    k_scatter2<<<NB_E, 256, 0, stream>>>(ei, cursor, perm);
    k_lin<<<782, 256, 0, stream>>>(obj, Wo, bo, OLb, N_NODES / 16);
    k_fl<<<2048, 256, 0, stream>>>(rel, ei, perm, Wr, br, OLb, Ysw);
    k_segsum<<<(N_NODES + 3) / 4, 256, 0, stream>>>(Ysw, OLb, offsets, out);
}

// Round 14
// 246.184 us; speedup vs baseline: 1.7312x; 1.7312x over previous
//
#include <hip/hip_runtime.h>

#define N_NODES 50000
#define N_EDGES 600000
#define DD 128

typedef __attribute__((ext_vector_type(8))) short short8;
typedef __attribute__((ext_vector_type(4))) float f32x4;

__device__ __forceinline__ short f2bf(float f) {
    union { float f; unsigned u; } v; v.f = f;
    unsigned r = v.u + 0x7fffu + ((v.u >> 16) & 1u);
    return (short)(r >> 16);
}
__device__ __forceinline__ float u2f(unsigned u) {
    union { float f; unsigned u; } v; v.u = u;
    return v.f;
}
__device__ __forceinline__ unsigned packbf(float a, float b) {
    return ((unsigned)(unsigned short)f2bf(a)) |
           (((unsigned)(unsigned short)f2bf(b)) << 16);
}

// ---------------------------------------------------------------------------
// Streaming GEMM: Y = X @ W^T + bias -> bf16 (obj_lin). W frag-major in LDS.
// (proven, R11)
// ---------------------------------------------------------------------------
__global__ __launch_bounds__(256) void k_lin(const float* __restrict__ X,
                                             const float* __restrict__ W,
                                             const float* __restrict__ bias,
                                             short* __restrict__ Y,
                                             int ntiles) {
    __shared__ __align__(16) short Wf[128 * 128];
    for (int i = threadIdx.x; i < 2048; i += 256) {
        const int fl = i & 63, fr = i >> 6;
        const int nt = fr >> 2, ks = fr & 3, fg = fl >> 4, fln = fl & 15;
        const float* s = W + (nt * 16 + fln) * DD + ks * 32 + fg * 8;
        short* d = Wf + i * 8;
#pragma unroll
        for (int j = 0; j < 8; ++j) d[j] = f2bf(s[j]);
    }
    __syncthreads();

    const int wave = threadIdx.x >> 6;
    const int lane = threadIdx.x & 63;
    const int g = lane >> 4, ln = lane & 15;

    float bb[8];
#pragma unroll
    for (int nt = 0; nt < 8; ++nt) bb[nt] = bias[nt * 16 + ln];

    for (int t = blockIdx.x * 4 + wave; t < ntiles; t += gridDim.x * 4) {
        const float* xr = X + (size_t)(t * 16 + ln) * DD;
        short8 a[4];
#pragma unroll
        for (int ks = 0; ks < 4; ++ks) {
            const f32x4* p = (const f32x4*)(xr + ks * 32 + g * 8);
            const f32x4 t0 = __builtin_nontemporal_load(p);
            const f32x4 t1 = __builtin_nontemporal_load(p + 1);
            short8 v;
            v[0] = f2bf(t0[0]); v[1] = f2bf(t0[1]); v[2] = f2bf(t0[2]); v[3] = f2bf(t0[3]);
            v[4] = f2bf(t1[0]); v[5] = f2bf(t1[1]); v[6] = f2bf(t1[2]); v[7] = f2bf(t1[3]);
            a[ks] = v;
        }
#pragma unroll
        for (int nt = 0; nt < 8; ++nt) {
            f32x4 acc = {0.f, 0.f, 0.f, 0.f};
#pragma unroll
            for (int ks = 0; ks < 4; ++ks) {
                short8 b = *(const short8*)(Wf + (((nt << 2) + ks) * 64 + lane) * 8);
                acc = __builtin_amdgcn_mfma_f32_16x16x32_bf16(a[ks], b, acc, 0, 0, 0);
            }
#pragma unroll
            for (int r = 0; r < 4; ++r)
                Y[(size_t)(t * 16 + g * 4 + r) * DD + nt * 16 + ln] = f2bf(acc[r] + bb[nt]);
        }
    }
}

// ---------------------------------------------------------------------------
// CSR-rank construction (counts zeroed by hipMemsetAsync)
// ---------------------------------------------------------------------------
__global__ __launch_bounds__(256) void k_count(const int* __restrict__ EI,
                                               int* __restrict__ counts) {
    int e = blockIdx.x * 256 + threadIdx.x;
    if (e < N_EDGES) atomicAdd(&counts[EI[2 * e + 1]], 1);
}

__global__ __launch_bounds__(256) void k_scan1(const int* __restrict__ counts,
                                               int* __restrict__ scanned,
                                               int* __restrict__ bsum) {
    __shared__ int tmp[256];
    const int t = threadIdx.x;
    const int i = blockIdx.x * 256 + t;
    int v = (i < N_NODES) ? counts[i] : 0;
    tmp[t] = v;
    __syncthreads();
#pragma unroll
    for (int off = 1; off < 256; off <<= 1) {
        int x = (t >= off) ? tmp[t - off] : 0;
        __syncthreads();
        tmp[t] += x;
        __syncthreads();
    }
    if (i < N_NODES) scanned[i] = tmp[t] - v;
    if (t == 255) bsum[blockIdx.x] = tmp[255];
}

__global__ __launch_bounds__(256) void k_scan3m(const int* __restrict__ scanned,
                                                const int* __restrict__ bsum,
                                                int* __restrict__ offsets,
                                                int* __restrict__ cursor,
                                                int nb) {
    __shared__ int red[256];
    const int t = threadIdx.x;
    const int bid = blockIdx.x;
    red[t] = (t < bid && t < nb) ? bsum[t] : 0;
    __syncthreads();
#pragma unroll
    for (int off = 128; off > 0; off >>= 1) {
        if (t < off) red[t] += red[t + off];
        __syncthreads();
    }
    const int pre = red[0];
    const int i = bid * 256 + t;
    if (i < N_NODES) {
        const int off = scanned[i] + pre;
        offsets[i] = off;
        cursor[i] = off;
    }
    if (i == 0) offsets[N_NODES] = N_EDGES;
}

__global__ __launch_bounds__(256) void k_scatter2(const int* __restrict__ EI,
                                                  int* __restrict__ cursor,
                                                  int* __restrict__ perm) {
    int e = blockIdx.x * 256 + threadIdx.x;
    if (e < N_EDGES)
        perm[e] = atomicAdd(&cursor[EI[2 * e + 1]], 1);
}

// ---------------------------------------------------------------------------
// Fused rel-GEMM + OL[src] add + scatter-write to dst-sorted position.
// R11 base; epilogue now batches all 16 pos/OL gathers into registers before
// the compute/store loop (16 loads in flight), and Ys stores are
// non-temporal (write-once stream; keep L2 for OL gathers). No VGPR cap.
// ---------------------------------------------------------------------------
__global__ __launch_bounds__(256) void k_fl(const float* __restrict__ RV,
                                            const int* __restrict__ EI,
                                            const int* __restrict__ perm,
                                            const float* __restrict__ W,
                                            const float* __restrict__ bias,
                                            const short* __restrict__ OL,
                                            unsigned* __restrict__ Ysw) {
    __shared__ __align__(16) short Wf[128 * 128];
    __shared__ __align__(16) unsigned stg[4][8 * 136];   // [e2][col], stride 136

    for (int i = threadIdx.x; i < 2048; i += 256) {
        const int fl = i & 63, fr = i >> 6;
        const int nt = fr >> 2, ks = fr & 3, fg = fl >> 4, fln = fl & 15;
        const float* s = W + (nt * 16 + fln) * DD + ks * 32 + fg * 8;
        short* d = Wf + i * 8;
#pragma unroll
        for (int j = 0; j < 8; ++j) d[j] = f2bf(s[j]);
    }
    __syncthreads();

    const int wave = threadIdx.x >> 6;
    const int lane = threadIdx.x & 63;
    const int g = lane >> 4, ln = lane & 15;
    unsigned* st = stg[wave];

    const float br0 = bias[2 * lane];
    const float br1 = bias[2 * lane + 1];
    const unsigned short* OLu = (const unsigned short*)OL;
    const int NT = N_EDGES / 16;                      // 37500 exact

    for (int t = blockIdx.x * 4 + wave; t < NT; t += gridDim.x * 4) {
        const int e0 = t * 16;

        // A-fragment: row ln <- rel_vecs[e0+ln] (sequential stream, nt-load)
        const float* xr = RV + (size_t)(e0 + ln) * DD;
        short8 a[4];
#pragma unroll
        for (int ks = 0; ks < 4; ++ks) {
            const f32x4* p = (const f32x4*)(xr + ks * 32 + g * 8);
            const f32x4 t0 = __builtin_nontemporal_load(p);
            const f32x4 t1 = __builtin_nontemporal_load(p + 1);
            short8 v;
            v[0] = f2bf(t0[0]); v[1] = f2bf(t0[1]); v[2] = f2bf(t0[2]); v[3] = f2bf(t0[3]);
            v[4] = f2bf(t1[0]); v[5] = f2bf(t1[1]); v[6] = f2bf(t1[2]); v[7] = f2bf(t1[3]);
            a[ks] = v;
        }

        // src + sorted position for the 16 edges (lanes 0..15 hold, shfl later)
        int sp = 0, pp = 0;
        if (lane < 16) {
            sp = EI[2 * (e0 + lane)];
            pp = perm[e0 + lane];
        }

        f32x4 acc[8];
#pragma unroll
        for (int nt = 0; nt < 8; ++nt) {
            acc[nt] = (f32x4){0.f, 0.f, 0.f, 0.f};
#pragma unroll
            for (int ks = 0; ks < 4; ++ks) {
                short8 b = *(const short8*)(Wf + (((nt << 2) + ks) * 64 + lane) * 8);
                acc[nt] = __builtin_amdgcn_mfma_f32_16x16x32_bf16(a[ks], b, acc[nt], 0, 0, 0);
            }
        }

        // stage: row e2 = g*2+(r>>1); word col = nt*16+ln; lo16 = even edge
#pragma unroll
        for (int nt = 0; nt < 8; ++nt) {
            const int c = nt * 16 + ln;
            st[(g * 2) * 136 + c]     = packbf(acc[nt][0], acc[nt][1]);
            st[(g * 2 + 1) * 136 + c] = packbf(acc[nt][2], acc[nt][3]);
        }

        // batched gathers: all 16 positions + OL words in flight first
        int pos16[16];
        unsigned ol16[16];
#pragma unroll
        for (int e = 0; e < 16; ++e) {
            const int src = __shfl(sp, e);
            pos16[e] = __shfl(pp, e);
            ol16[e] = *(const unsigned*)(OLu + (size_t)src * DD + 2 * lane);
        }

        // compute + nt scatter stores; cols (2*lane, 2*lane+1)
#pragma unroll
        for (int ep = 0; ep < 8; ++ep) {
            const unsigned qx = st[ep * 136 + 2 * lane];
            const unsigned qy = st[ep * 136 + 2 * lane + 1];
#pragma unroll
            for (int sub = 0; sub < 2; ++sub) {
                const int e = 2 * ep + sub;
                const float s0 = sub ? u2f(qx & 0xffff0000u) : u2f(qx << 16);
                const float s1 = sub ? u2f(qy & 0xffff0000u) : u2f(qy << 16);
                const float y0 = s0 + br0 + u2f(ol16[e] << 16);
                const float y1 = s1 + br1 + u2f(ol16[e] & 0xffff0000u);
                __builtin_nontemporal_store(packbf(y0, y1),
                    Ysw + (size_t)pos16[e] * (DD / 2) + lane);
            }
        }
    }
}

// ---------------------------------------------------------------------------
// Segment sum: one wave per node; lanes 0-31 even rows, 32-63 odd rows,
// 8B loads; shfl_xor(32) finish. Writes every node (deg-0 -> 0).
// (proven, R11)
// ---------------------------------------------------------------------------
__global__ __launch_bounds__(256) void k_segsum(const unsigned* __restrict__ Ysw,
                                                const short* __restrict__ OL,
                                                const int* __restrict__ offs,
                                                float* __restrict__ out) {
    const int wave = threadIdx.x >> 6;
    const int lane = threadIdx.x & 63;
    const int v = blockIdx.x * 4 + wave;
    if (v >= N_NODES) return;

    const int r0 = offs[v], r1 = offs[v + 1];
    const int half = lane >> 5;
    const int q = lane & 31;
    const unsigned short* OLu = (const unsigned short*)OL;

    const uint2 odw = *(const uint2*)(OLu + (size_t)v * DD + 4 * q);
    const float od0 = u2f(odw.x << 16), od1 = u2f(odw.x & 0xffff0000u);
    const float od2 = u2f(odw.y << 16), od3 = u2f(odw.y & 0xffff0000u);

    float a0 = 0.f, a1 = 0.f, a2 = 0.f, a3 = 0.f;
    for (int r = r0 + half; r < r1; r += 2) {
        const uint2 y = *(const uint2*)(Ysw + (size_t)r * (DD / 2) + 2 * q);
        a0 += fmaxf(u2f(y.x << 16) + od0, 0.f);
        a1 += fmaxf(u2f(y.x & 0xffff0000u) + od1, 0.f);
        a2 += fmaxf(u2f(y.y << 16) + od2, 0.f);
        a3 += fmaxf(u2f(y.y & 0xffff0000u) + od3, 0.f);
    }
    a0 += __shfl_xor(a0, 32);
    a1 += __shfl_xor(a1, 32);
    a2 += __shfl_xor(a2, 32);
    a3 += __shfl_xor(a3, 32);

    if (half == 0) {
        float4 o;
        o.x = fmaxf(a0, 0.f); o.y = fmaxf(a1, 0.f);
        o.z = fmaxf(a2, 0.f); o.w = fmaxf(a3, 0.f);
        *(float4*)(out + (size_t)v * DD + 4 * q) = o;
    }
}

// ---------------------------------------------------------------------------
extern "C" void kernel_launch(void* const* d_in, const int* in_sizes, int n_in,
                              void* d_out, int out_size, void* d_ws, size_t ws_size,
                              hipStream_t stream) {
    const float* obj = (const float*)d_in[0];
    const float* rel = (const float*)d_in[1];
    const int*   ei  = (const int*)d_in[2];
    const float* Wo  = (const float*)d_in[3];
    const float* bo  = (const float*)d_in[4];
    const float* Wr  = (const float*)d_in[5];
    const float* br  = (const float*)d_in[6];
    float* out = (float*)d_out;

    char* ws = (char*)d_ws;
    unsigned* Ysw  = (unsigned*)ws;                  // 153,600,000 B
    short* OLb     = (short*)(ws + 153600000);       //  12,800,000 B
    int*   perm    = (int*)(ws + 166400000);         //   2,400,000 B
    int*   counts  = (int*)(ws + 168800000);         //     200,000 B
    int*   scanned = (int*)(ws + 169000192);         //     200,704 B
    int*   offsets = (int*)(ws + 169200896);         //     200,704 B (50001 ints)
    int*   cursor  = (int*)(ws + 169401600);         //     200,000 B
    int*   bsum    = (int*)(ws + 169601792);         //       1,024 B

    const int NB_E = (N_EDGES + 255) / 256;          // 2344
    const int NB_N = (N_NODES + 255) / 256;          // 196

    hipMemsetAsync(counts, 0, N_NODES * sizeof(int), stream);
    k_count<<<NB_E, 256, 0, stream>>>(ei, counts);
    k_scan1<<<NB_N, 256, 0, stream>>>(counts, scanned, bsum);
    k_scan3m<<<NB_N, 256, 0, stream>>>(scanned, bsum, offsets, cursor, NB_N);
    k_scatter2<<<NB_E, 256, 0, stream>>>(ei, cursor, perm);
    k_lin<<<782, 256, 0, stream>>>(obj, Wo, bo, OLb, N_NODES / 16);
    k_fl<<<2048, 256, 0, stream>>>(rel, ei, perm, Wr, br, OLb, Ysw);
    k_segsum<<<(N_NODES + 3) / 4, 256, 0, stream>>>(Ysw, OLb, offsets, out);
}

// Round 15
// 238.175 us; speedup vs baseline: 1.7895x; 1.0336x over previous
//
#include <hip/hip_runtime.h>

#define N_NODES 50000
#define N_EDGES 600000
#define DD 128

typedef __attribute__((ext_vector_type(8))) short short8;
typedef __attribute__((ext_vector_type(4))) float f32x4;

__device__ __forceinline__ short f2bf(float f) {
    union { float f; unsigned u; } v; v.f = f;
    unsigned r = v.u + 0x7fffu + ((v.u >> 16) & 1u);
    return (short)(r >> 16);
}
__device__ __forceinline__ float bf2f(short s) {
    union { float f; unsigned u; } v; v.u = ((unsigned)(unsigned short)s) << 16;
    return v.f;
}
__device__ __forceinline__ float u2f(unsigned u) {
    union { float f; unsigned u; } v; v.u = u;
    return v.f;
}
__device__ __forceinline__ unsigned packbf(float a, float b) {
    return ((unsigned)(unsigned short)f2bf(a)) |
           (((unsigned)(unsigned short)f2bf(b)) << 16);
}

// ---------------------------------------------------------------------------
// Streaming GEMM: Y = X @ W^T + bias -> bf16 (obj_lin). W frag-major in LDS.
// X loads non-temporal (read-once stream).
// ---------------------------------------------------------------------------
__global__ __launch_bounds__(256) void k_lin(const float* __restrict__ X,
                                             const float* __restrict__ W,
                                             const float* __restrict__ bias,
                                             short* __restrict__ Y,
                                             int ntiles) {
    __shared__ __align__(16) short Wf[128 * 128];
    for (int i = threadIdx.x; i < 2048; i += 256) {
        const int fl = i & 63, fr = i >> 6;
        const int nt = fr >> 2, ks = fr & 3, fg = fl >> 4, fln = fl & 15;
        const float* s = W + (nt * 16 + fln) * DD + ks * 32 + fg * 8;
        short* d = Wf + i * 8;
#pragma unroll
        for (int j = 0; j < 8; ++j) d[j] = f2bf(s[j]);
    }
    __syncthreads();

    const int wave = threadIdx.x >> 6;
    const int lane = threadIdx.x & 63;
    const int g = lane >> 4, ln = lane & 15;

    float bb[8];
#pragma unroll
    for (int nt = 0; nt < 8; ++nt) bb[nt] = bias[nt * 16 + ln];

    for (int t = blockIdx.x * 4 + wave; t < ntiles; t += gridDim.x * 4) {
        const float* xr = X + (size_t)(t * 16 + ln) * DD;
        short8 a[4];
#pragma unroll
        for (int ks = 0; ks < 4; ++ks) {
            const f32x4* p = (const f32x4*)(xr + ks * 32 + g * 8);
            const f32x4 t0 = __builtin_nontemporal_load(p);
            const f32x4 t1 = __builtin_nontemporal_load(p + 1);
            short8 v;
            v[0] = f2bf(t0[0]); v[1] = f2bf(t0[1]); v[2] = f2bf(t0[2]); v[3] = f2bf(t0[3]);
            v[4] = f2bf(t1[0]); v[5] = f2bf(t1[1]); v[6] = f2bf(t1[2]); v[7] = f2bf(t1[3]);
            a[ks] = v;
        }
#pragma unroll
        for (int nt = 0; nt < 8; ++nt) {
            f32x4 acc = {0.f, 0.f, 0.f, 0.f};
#pragma unroll
            for (int ks = 0; ks < 4; ++ks) {
                short8 b = *(const short8*)(Wf + (((nt << 2) + ks) * 64 + lane) * 8);
                acc = __builtin_amdgcn_mfma_f32_16x16x32_bf16(a[ks], b, acc, 0, 0, 0);
            }
#pragma unroll
            for (int r = 0; r < 4; ++r)
                Y[(size_t)(t * 16 + g * 4 + r) * DD + nt * 16 + ln] = f2bf(acc[r] + bb[nt]);
        }
    }
}

// ---------------------------------------------------------------------------
// CSR-rank construction (counts zeroed by hipMemsetAsync)
// ---------------------------------------------------------------------------
__global__ __launch_bounds__(256) void k_count(const int* __restrict__ EI,
                                               int* __restrict__ counts) {
    int e = blockIdx.x * 256 + threadIdx.x;
    if (e < N_EDGES) atomicAdd(&counts[EI[2 * e + 1]], 1);
}

__global__ __launch_bounds__(256) void k_scan1(const int* __restrict__ counts,
                                               int* __restrict__ scanned,
                                               int* __restrict__ bsum) {
    __shared__ int tmp[256];
    const int t = threadIdx.x;
    const int i = blockIdx.x * 256 + t;
    int v = (i < N_NODES) ? counts[i] : 0;
    tmp[t] = v;
    __syncthreads();
#pragma unroll
    for (int off = 1; off < 256; off <<= 1) {
        int x = (t >= off) ? tmp[t - off] : 0;
        __syncthreads();
        tmp[t] += x;
        __syncthreads();
    }
    if (i < N_NODES) scanned[i] = tmp[t] - v;
    if (t == 255) bsum[blockIdx.x] = tmp[255];
}

__global__ __launch_bounds__(256) void k_scan3m(const int* __restrict__ scanned,
                                                const int* __restrict__ bsum,
                                                int* __restrict__ offsets,
                                                int* __restrict__ cursor,
                                                int nb) {
    __shared__ int red[256];
    const int t = threadIdx.x;
    const int bid = blockIdx.x;
    red[t] = (t < bid && t < nb) ? bsum[t] : 0;
    __syncthreads();
#pragma unroll
    for (int off = 128; off > 0; off >>= 1) {
        if (t < off) red[t] += red[t + off];
        __syncthreads();
    }
    const int pre = red[0];
    const int i = bid * 256 + t;
    if (i < N_NODES) {
        const int off = scanned[i] + pre;
        offsets[i] = off;
        cursor[i] = off;
    }
    if (i == 0) offsets[N_NODES] = N_EDGES;
}

__global__ __launch_bounds__(256) void k_scatter2(const int* __restrict__ EI,
                                                  int* __restrict__ cursor,
                                                  int* __restrict__ perm) {
    int e = blockIdx.x * 256 + threadIdx.x;
    if (e < N_EDGES)
        perm[e] = atomicAdd(&cursor[EI[2 * e + 1]], 1);
}

// ---------------------------------------------------------------------------
// Fused rel-GEMM + OL[src] add + scatter-write to dst-sorted position.
// RV loads non-temporal (don't evict Ys from L3). Stage layout [e2][col],
// stride 136 words: 2-way-free stage writes, paired epilogue reads.
// ---------------------------------------------------------------------------
__global__ __launch_bounds__(256) void k_fl(const float* __restrict__ RV,
                                            const int* __restrict__ EI,
                                            const int* __restrict__ perm,
                                            const float* __restrict__ W,
                                            const float* __restrict__ bias,
                                            const short* __restrict__ OL,
                                            unsigned* __restrict__ Ysw) {
    __shared__ __align__(16) short Wf[128 * 128];
    __shared__ __align__(16) unsigned stg[4][8 * 136];   // [e2][col], stride 136

    for (int i = threadIdx.x; i < 2048; i += 256) {
        const int fl = i & 63, fr = i >> 6;
        const int nt = fr >> 2, ks = fr & 3, fg = fl >> 4, fln = fl & 15;
        const float* s = W + (nt * 16 + fln) * DD + ks * 32 + fg * 8;
        short* d = Wf + i * 8;
#pragma unroll
        for (int j = 0; j < 8; ++j) d[j] = f2bf(s[j]);
    }
    __syncthreads();

    const int wave = threadIdx.x >> 6;
    const int lane = threadIdx.x & 63;
    const int g = lane >> 4, ln = lane & 15;
    unsigned* st = stg[wave];

    const float br0 = bias[2 * lane];
    const float br1 = bias[2 * lane + 1];
    const unsigned short* OLu = (const unsigned short*)OL;
    const int NT = N_EDGES / 16;                      // 37500 exact

    for (int t = blockIdx.x * 4 + wave; t < NT; t += gridDim.x * 4) {
        const int e0 = t * 16;

        // A-fragment: row ln <- rel_vecs[e0+ln] (sequential stream, nt-load)
        const float* xr = RV + (size_t)(e0 + ln) * DD;
        short8 a[4];
#pragma unroll
        for (int ks = 0; ks < 4; ++ks) {
            const f32x4* p = (const f32x4*)(xr + ks * 32 + g * 8);
            const f32x4 t0 = __builtin_nontemporal_load(p);
            const f32x4 t1 = __builtin_nontemporal_load(p + 1);
            short8 v;
            v[0] = f2bf(t0[0]); v[1] = f2bf(t0[1]); v[2] = f2bf(t0[2]); v[3] = f2bf(t0[3]);
            v[4] = f2bf(t1[0]); v[5] = f2bf(t1[1]); v[6] = f2bf(t1[2]); v[7] = f2bf(t1[3]);
            a[ks] = v;
        }

        // src + sorted position for the 16 edges (lanes 0..15 load, shfl later)
        int sp = 0, pp = 0;
        if (lane < 16) {
            sp = EI[2 * (e0 + lane)];
            pp = perm[e0 + lane];
        }

        f32x4 acc[8];
#pragma unroll
        for (int nt = 0; nt < 8; ++nt) {
            acc[nt] = (f32x4){0.f, 0.f, 0.f, 0.f};
#pragma unroll
            for (int ks = 0; ks < 4; ++ks) {
                short8 b = *(const short8*)(Wf + (((nt << 2) + ks) * 64 + lane) * 8);
                acc[nt] = __builtin_amdgcn_mfma_f32_16x16x32_bf16(a[ks], b, acc[nt], 0, 0, 0);
            }
        }

        // stage: row e2 = g*2 + (r>>1); word col = nt*16+ln; lo16=even edge
#pragma unroll
        for (int nt = 0; nt < 8; ++nt) {
            const int c = nt * 16 + ln;
            st[(g * 2) * 136 + c]     = packbf(acc[nt][0], acc[nt][1]);
            st[(g * 2 + 1) * 136 + c] = packbf(acc[nt][2], acc[nt][3]);
        }

        // epilogue: per edge-pair hoisted reads; cols (2*lane, 2*lane+1)
#pragma unroll
        for (int ep = 0; ep < 8; ++ep) {
            const unsigned qx = st[ep * 136 + 2 * lane];
            const unsigned qy = st[ep * 136 + 2 * lane + 1];
#pragma unroll
            for (int sub = 0; sub < 2; ++sub) {
                const int e = 2 * ep + sub;
                const int src = __shfl(sp, e);
                const int pos = __shfl(pp, e);
                const float s0 = sub ? u2f(qx & 0xffff0000u) : u2f(qx << 16);
                const float s1 = sub ? u2f(qy & 0xffff0000u) : u2f(qy << 16);
                const unsigned olw = *(const unsigned*)(OLu + (size_t)src * DD + 2 * lane);
                const float y0 = s0 + br0 + u2f(olw << 16);
                const float y1 = s1 + br1 + u2f(olw & 0xffff0000u);
                Ysw[(size_t)pos * (DD / 2) + lane] = packbf(y0, y1);
            }
        }
    }
}

// ---------------------------------------------------------------------------
// Segment sum: one wave per node; lanes 0-31 even rows, 32-63 odd rows,
// 8B loads (wave = 2 full rows / instruction); shfl_xor(32) finish.
// Writes every node (deg-0 -> 0): subsumes zero + final relu.
// ---------------------------------------------------------------------------
__global__ __launch_bounds__(256) void k_segsum(const unsigned* __restrict__ Ysw,
                                                const short* __restrict__ OL,
                                                const int* __restrict__ offs,
                                                float* __restrict__ out) {
    const int wave = threadIdx.x >> 6;
    const int lane = threadIdx.x & 63;
    const int v = blockIdx.x * 4 + wave;
    if (v >= N_NODES) return;

    const int r0 = offs[v], r1 = offs[v + 1];
    const int half = lane >> 5;
    const int q = lane & 31;
    const unsigned short* OLu = (const unsigned short*)OL;

    const uint2 odw = *(const uint2*)(OLu + (size_t)v * DD + 4 * q);
    const float od0 = u2f(odw.x << 16), od1 = u2f(odw.x & 0xffff0000u);
    const float od2 = u2f(odw.y << 16), od3 = u2f(odw.y & 0xffff0000u);

    float a0 = 0.f, a1 = 0.f, a2 = 0.f, a3 = 0.f;
    for (int r = r0 + half; r < r1; r += 2) {
        const uint2 y = *(const uint2*)(Ysw + (size_t)r * (DD / 2) + 2 * q);
        a0 += fmaxf(u2f(y.x << 16) + od0, 0.f);
        a1 += fmaxf(u2f(y.x & 0xffff0000u) + od1, 0.f);
        a2 += fmaxf(u2f(y.y << 16) + od2, 0.f);
        a3 += fmaxf(u2f(y.y & 0xffff0000u) + od3, 0.f);
    }
    a0 += __shfl_xor(a0, 32);
    a1 += __shfl_xor(a1, 32);
    a2 += __shfl_xor(a2, 32);
    a3 += __shfl_xor(a3, 32);

    if (half == 0) {
        float4 o;
        o.x = fmaxf(a0, 0.f); o.y = fmaxf(a1, 0.f);
        o.z = fmaxf(a2, 0.f); o.w = fmaxf(a3, 0.f);
        *(float4*)(out + (size_t)v * DD + 4 * q) = o;
    }
}

// ---------------------------------------------------------------------------
extern "C" void kernel_launch(void* const* d_in, const int* in_sizes, int n_in,
                              void* d_out, int out_size, void* d_ws, size_t ws_size,
                              hipStream_t stream) {
    const float* obj = (const float*)d_in[0];
    const float* rel = (const float*)d_in[1];
    const int*   ei  = (const int*)d_in[2];
    const float* Wo  = (const float*)d_in[3];
    const float* bo  = (const float*)d_in[4];
    const float* Wr  = (const float*)d_in[5];
    const float* br  = (const float*)d_in[6];
    float* out = (float*)d_out;

    char* ws = (char*)d_ws;
    unsigned* Ysw  = (unsigned*)ws;                  // 153,600,000 B
    short* OLb     = (short*)(ws + 153600000);       //  12,800,000 B
    int*   perm    = (int*)(ws + 166400000);         //   2,400,000 B
    int*   counts  = (int*)(ws + 168800000);         //     200,000 B
    int*   scanned = (int*)(ws + 169000192);         //     200,704 B
    int*   offsets = (int*)(ws + 169200896);         //     200,704 B (50001 ints)
    int*   cursor  = (int*)(ws + 169401600);         //     200,000 B
    int*   bsum    = (int*)(ws + 169601792);         //       1,024 B

    const int NB_E = (N_EDGES + 255) / 256;          // 2344
    const int NB_N = (N_NODES + 255) / 256;          // 196

    hipMemsetAsync(counts, 0, N_NODES * sizeof(int), stream);
    k_count<<<NB_E, 256, 0, stream>>>(ei, counts);
    k_scan1<<<NB_N, 256, 0, stream>>>(counts, scanned, bsum);
    k_scan3m<<<NB_N, 256, 0, stream>>>(scanned, bsum, offsets, cursor, NB_N);
    k_scatter2<<<NB_E, 256, 0, stream>>>(ei, cursor, perm);
    k_lin<<<782, 256, 0, stream>>>(obj, Wo, bo, OLb, N_NODES / 16);
    k_fl<<<2048, 256, 0, stream>>>(rel, ei, perm, Wr, br, OLb, Ysw);
    k_segsum<<<(N_NODES + 3) / 4, 256, 0, stream>>>(Ysw, OLb, offsets, out);
}